// Round 1
// baseline (4854.488 us; speedup 1.0000x reference)
//
#include <hip/hip_runtime.h>
#include <math.h>

#define NB 4
#define NT 2048
#define NC 1024
#define NHEADS 16
#define HDIM 64

// ---------------------------------------------------------------------------
// Kernel 1: qkv = x @ w^T + b, fused RoPE (+*pe_scale for q, /pe_scale for k),
// scatter into q/k/v workspace with layout (B, NH, T, D), fp32.
// M = B*T = 8192, N = 3*C = 3072, K = C = 1024.
// Tile 128x128x16, 256 threads, 8x8 micro-tile per thread.
// ---------------------------------------------------------------------------
__global__ __launch_bounds__(256) void qkv_rope_kernel(
    const float* __restrict__ x, const float* __restrict__ w,
    const float* __restrict__ bias, const float* __restrict__ pe_cos,
    const float* __restrict__ pe_sin, const float* __restrict__ pe_scale,
    float* __restrict__ qout, float* __restrict__ kout, float* __restrict__ vout)
{
    __shared__ float As[128][16];
    __shared__ float Bs[128][16];
    const int tid = threadIdx.x;
    const int tx = tid & 15;
    const int ty = tid >> 4;
    const int m0 = blockIdx.x * 128;
    const int n0 = blockIdx.y * 128;

    float acc[8][8];
#pragma unroll
    for (int i = 0; i < 8; ++i)
#pragma unroll
        for (int j = 0; j < 8; ++j) acc[i][j] = 0.f;

    const int lrow = tid >> 2;          // 0..63
    const int lcol = (tid & 3) << 2;    // 0,4,8,12

    const float* xA0 = &x[(size_t)(m0 + lrow) * NC + lcol];
    const float* xA1 = &x[(size_t)(m0 + lrow + 64) * NC + lcol];
    const float* wB0 = &w[(size_t)(n0 + lrow) * NC + lcol];
    const float* wB1 = &w[(size_t)(n0 + lrow + 64) * NC + lcol];

    for (int k0 = 0; k0 < NC; k0 += 16) {
        const float4 a0 = *(const float4*)(xA0 + k0);
        const float4 a1 = *(const float4*)(xA1 + k0);
        const float4 b0 = *(const float4*)(wB0 + k0);
        const float4 b1 = *(const float4*)(wB1 + k0);
        __syncthreads();
        *(float4*)&As[lrow][lcol]      = a0;
        *(float4*)&As[lrow + 64][lcol] = a1;
        *(float4*)&Bs[lrow][lcol]      = b0;
        *(float4*)&Bs[lrow + 64][lcol] = b1;
        __syncthreads();
#pragma unroll
        for (int kk = 0; kk < 16; kk += 4) {
            float4 af[8], bf[8];
#pragma unroll
            for (int i = 0; i < 8; ++i) af[i] = *(const float4*)&As[ty * 8 + i][kk];
#pragma unroll
            for (int j = 0; j < 8; ++j) bf[j] = *(const float4*)&Bs[tx * 8 + j][kk];
#pragma unroll
            for (int i = 0; i < 8; ++i)
#pragma unroll
                for (int j = 0; j < 8; ++j) {
                    acc[i][j] = fmaf(af[i].x, bf[j].x, acc[i][j]);
                    acc[i][j] = fmaf(af[i].y, bf[j].y, acc[i][j]);
                    acc[i][j] = fmaf(af[i].z, bf[j].z, acc[i][j]);
                    acc[i][j] = fmaf(af[i].w, bf[j].w, acc[i][j]);
                }
        }
    }

    // Epilogue: bias + RoPE + scatter.
    const int ncol = n0 + tx * 8;       // 8 consecutive cols, even-aligned, same head
    const int part = ncol >> 10;        // 0=q, 1=k, 2=v
    const int h    = (ncol & 1023) >> 6;
    const int dd   = ncol & 63;
    float bv[8];
#pragma unroll
    for (int j = 0; j < 8; ++j) bv[j] = bias[ncol + j];
    float* outp = (part == 0) ? qout : ((part == 1) ? kout : vout);

#pragma unroll
    for (int i = 0; i < 8; ++i) {
        const int m  = m0 + ty * 8 + i;
        const int bb = m >> 11;         // T = 2048
        const int t  = m & 2047;
        float vals[8];
#pragma unroll
        for (int j = 0; j < 8; ++j) vals[j] = acc[i][j] + bv[j];
        if (part < 2) {
            const float* cp  = &pe_cos[t * HDIM + dd];
            const float* sp  = &pe_sin[t * HDIM + dd];
            const float* scp = &pe_scale[t * HDIM + dd];
#pragma unroll
            for (int j = 0; j < 8; j += 2) {
                const float e = vals[j], o = vals[j + 1];
                // rot[2i] = -u[2i+1], rot[2i+1] = u[2i]
                float r0 = e * cp[j]     - o * sp[j];
                float r1 = o * cp[j + 1] + e * sp[j + 1];
                const float s0 = scp[j], s1 = scp[j + 1];
                if (part == 0) { r0 *= s0; r1 *= s1; }
                else           { r0 /= s0; r1 /= s1; }
                vals[j] = r0; vals[j + 1] = r1;
            }
        }
        const size_t off = (((size_t)(bb * NHEADS + h)) * NT + t) * HDIM + dd;
        *(float4*)&outp[off]     = make_float4(vals[0], vals[1], vals[2], vals[3]);
        *(float4*)&outp[off + 4] = make_float4(vals[4], vals[5], vals[6], vals[7]);
    }
}

// ---------------------------------------------------------------------------
// Kernel 2: flash attention, fp32. One block = (b, h, 64 q-rows).
// scores = (q.k) * 1/sqrt(128) + mask[b,q,k]; online softmax; out = P@V / l.
// Output layout (B, T, NH, D).
// ---------------------------------------------------------------------------
__global__ __launch_bounds__(256) void attn_kernel(
    const float* __restrict__ q, const float* __restrict__ k,
    const float* __restrict__ v, const float* __restrict__ mask,
    float* __restrict__ out)
{
    __shared__ float Qs[64][64];
    __shared__ float Ks[64][64];
    __shared__ float Vs[64][64];
    __shared__ float Ps[64][64];
    const int tid = threadIdx.x;
    const int tx = tid & 15;
    const int ty = tid >> 4;
    const int q0 = blockIdx.x * 64;
    const int h  = blockIdx.y;
    const int b  = blockIdx.z;

    const size_t bh = (size_t)b * NHEADS + h;
    const float* qp = q + (bh * NT + q0) * HDIM;
    const float* kp = k + bh * NT * HDIM;
    const float* vp = v + bh * NT * HDIM;
    const float* mp = mask + ((size_t)b * NT + q0) * NT;

    // Q tile is contiguous 16KB: flat float4 copy.
    {
        const float4* src = (const float4*)qp;
        float4* dst = (float4*)&Qs[0][0];
#pragma unroll
        for (int p = 0; p < 4; ++p) dst[tid + p * 256] = src[tid + p * 256];
    }

    float acc[4][4];
    float mi[4], li[4];
#pragma unroll
    for (int i = 0; i < 4; ++i) {
        mi[i] = -INFINITY; li[i] = 0.f;
#pragma unroll
        for (int j = 0; j < 4; ++j) acc[i][j] = 0.f;
    }
    const float scale = 0.08838834764831845f;  // 1/sqrt(2*D)

    for (int kt = 0; kt < NT / 64; ++kt) {
        __syncthreads();   // previous PV (Ps,Vs reads) done before overwrite
        {
            const float4* ksrc = (const float4*)(kp + (size_t)kt * 64 * HDIM);
            const float4* vsrc = (const float4*)(vp + (size_t)kt * 64 * HDIM);
            float4* kd = (float4*)&Ks[0][0];
            float4* vd = (float4*)&Vs[0][0];
#pragma unroll
            for (int p = 0; p < 4; ++p) {
                kd[tid + p * 256] = ksrc[tid + p * 256];
                vd[tid + p * 256] = vsrc[tid + p * 256];
            }
        }
        __syncthreads();

        float s[4][4];
#pragma unroll
        for (int i = 0; i < 4; ++i)
#pragma unroll
            for (int j = 0; j < 4; ++j) s[i][j] = 0.f;

#pragma unroll 4
        for (int d4 = 0; d4 < 16; ++d4) {
            float4 qf[4], kf[4];
#pragma unroll
            for (int i = 0; i < 4; ++i) qf[i] = *(const float4*)&Qs[ty * 4 + i][d4 * 4];
#pragma unroll
            for (int j = 0; j < 4; ++j) kf[j] = *(const float4*)&Ks[tx * 4 + j][d4 * 4];
#pragma unroll
            for (int i = 0; i < 4; ++i)
#pragma unroll
                for (int j = 0; j < 4; ++j) {
                    s[i][j] = fmaf(qf[i].x, kf[j].x, s[i][j]);
                    s[i][j] = fmaf(qf[i].y, kf[j].y, s[i][j]);
                    s[i][j] = fmaf(qf[i].z, kf[j].z, s[i][j]);
                    s[i][j] = fmaf(qf[i].w, kf[j].w, s[i][j]);
                }
        }

        // scale + mask + online softmax update
#pragma unroll
        for (int i = 0; i < 4; ++i) {
            const float4 mr = *(const float4*)&mp[(size_t)(ty * 4 + i) * NT + kt * 64 + tx * 4];
            s[i][0] = fmaf(s[i][0], scale, mr.x);
            s[i][1] = fmaf(s[i][1], scale, mr.y);
            s[i][2] = fmaf(s[i][2], scale, mr.z);
            s[i][3] = fmaf(s[i][3], scale, mr.w);

            float rm = fmaxf(fmaxf(s[i][0], s[i][1]), fmaxf(s[i][2], s[i][3]));
#pragma unroll
            for (int off = 1; off < 16; off <<= 1)
                rm = fmaxf(rm, __shfl_xor(rm, off, 64));
            const float mnew  = fmaxf(mi[i], rm);
            const float alpha = __expf(mi[i] - mnew);
            const float p0 = __expf(s[i][0] - mnew);
            const float p1 = __expf(s[i][1] - mnew);
            const float p2 = __expf(s[i][2] - mnew);
            const float p3 = __expf(s[i][3] - mnew);
            float rs = p0 + p1 + p2 + p3;
#pragma unroll
            for (int off = 1; off < 16; off <<= 1)
                rs += __shfl_xor(rs, off, 64);
            li[i] = li[i] * alpha + rs;
            mi[i] = mnew;
#pragma unroll
            for (int j = 0; j < 4; ++j) acc[i][j] *= alpha;
            *(float4*)&Ps[ty * 4 + i][tx * 4] = make_float4(p0, p1, p2, p3);
        }
        __syncthreads();

        // acc += P @ V
#pragma unroll 4
        for (int k4 = 0; k4 < 16; ++k4) {
            float4 pf[4];
#pragma unroll
            for (int i = 0; i < 4; ++i) pf[i] = *(const float4*)&Ps[ty * 4 + i][k4 * 4];
            float pa[4][4];
#pragma unroll
            for (int i = 0; i < 4; ++i) {
                pa[i][0] = pf[i].x; pa[i][1] = pf[i].y; pa[i][2] = pf[i].z; pa[i][3] = pf[i].w;
            }
#pragma unroll
            for (int c = 0; c < 4; ++c) {
                const float4 vf = *(const float4*)&Vs[k4 * 4 + c][tx * 4];
#pragma unroll
                for (int i = 0; i < 4; ++i) {
                    acc[i][0] = fmaf(pa[i][c], vf.x, acc[i][0]);
                    acc[i][1] = fmaf(pa[i][c], vf.y, acc[i][1]);
                    acc[i][2] = fmaf(pa[i][c], vf.z, acc[i][2]);
                    acc[i][3] = fmaf(pa[i][c], vf.w, acc[i][3]);
                }
            }
        }
    }

    // out[b][t][h][d] = acc / l  (output layout (B,T,NH,D))
#pragma unroll
    for (int i = 0; i < 4; ++i) {
        const float inv = 1.f / li[i];
        const int t = q0 + ty * 4 + i;
        const size_t off = (((size_t)b * NT + t) * NHEADS + h) * HDIM + tx * 4;
        *(float4*)&out[off] =
            make_float4(acc[i][0] * inv, acc[i][1] * inv, acc[i][2] * inv, acc[i][3] * inv);
    }
}

extern "C" void kernel_launch(void* const* d_in, const int* in_sizes, int n_in,
                              void* d_out, int out_size, void* d_ws, size_t ws_size,
                              hipStream_t stream) {
    const float* x        = (const float*)d_in[0];
    const float* pe_cos   = (const float*)d_in[1];
    const float* pe_sin   = (const float*)d_in[2];
    const float* pe_scale = (const float*)d_in[3];
    const float* mask     = (const float*)d_in[4];
    const float* w_qkv    = (const float*)d_in[5];
    const float* b_qkv    = (const float*)d_in[6];
    float* out = (float*)d_out;

    const size_t per = (size_t)NB * NHEADS * NT * HDIM;  // 8388608 floats
    float* qw = (float*)d_ws;
    float* kw = qw + per;
    float* vw = kw + per;

    qkv_rope_kernel<<<dim3(64, 24), 256, 0, stream>>>(
        x, w_qkv, b_qkv, pe_cos, pe_sin, pe_scale, qw, kw, vw);
    attn_kernel<<<dim3(NT / 64, NHEADS, NB), 256, 0, stream>>>(
        qw, kw, vw, mask, out);
}

// Round 3
// 446.271 us; speedup vs baseline: 10.8779x; 10.8779x over previous
//
#include <hip/hip_runtime.h>
#include <math.h>

#define NB 4
#define NT 2048
#define NC 1024
#define NHEADS 16
#define HDIM 64

typedef __attribute__((ext_vector_type(8))) short short8v;
typedef __attribute__((ext_vector_type(4))) float f32x4;

__device__ inline unsigned short f2bf(float f) {
    unsigned int u = __float_as_uint(f);
    u += 0x7FFFu + ((u >> 16) & 1u);
    return (unsigned short)(u >> 16);
}
__device__ inline float bf2f(unsigned short h) {
    return __uint_as_float(((unsigned int)h) << 16);
}

#define AS1C(p) ((const __attribute__((address_space(1))) unsigned int*)(unsigned long long)(const void*)(p))
#define AS3P(p) ((__attribute__((address_space(3))) unsigned int*)(unsigned int)(unsigned long long)(void*)(p))
#define GLL16(gp, lp) __builtin_amdgcn_global_load_lds(AS1C(gp), AS3P(lp), 16, 0, 0)

// ---------------------------------------------------------------------------
// split fp32 -> bf16 hi + bf16 lo
// ---------------------------------------------------------------------------
__global__ __launch_bounds__(256) void split_bf16_kernel(
    const float* __restrict__ in, unsigned short* __restrict__ hi,
    unsigned short* __restrict__ lo, int n4)
{
    const int i = blockIdx.x * 256 + threadIdx.x;
    if (i >= n4) return;
    const float4 f = ((const float4*)in)[i];
    ushort4 h, l;
    h.x = f2bf(f.x); l.x = f2bf(f.x - bf2f(h.x));
    h.y = f2bf(f.y); l.y = f2bf(f.y - bf2f(h.y));
    h.z = f2bf(f.z); l.z = f2bf(f.z - bf2f(h.z));
    h.w = f2bf(f.w); l.w = f2bf(f.w - bf2f(h.w));
    ((ushort4*)hi)[i] = h;
    ((ushort4*)lo)[i] = l;
}

// ---------------------------------------------------------------------------
// Kernel 1: qkv = x @ w^T + b via split-bf16 MFMA (AhBh + AhBl + AlBh),
// fused RoPE epilogue. q,k written bf16 (B,NH,T,D); v written TRANSPOSED
// bf16 (B,NH,D,T) so attention's PV B-operand reads are linear.
// M=8192, N=3072, K=1024. Tile 128x128x32, 4 waves, 64x64 per wave.
// ---------------------------------------------------------------------------
__global__ __launch_bounds__(256) void qkv_gemm_kernel(
    const unsigned short* __restrict__ xh, const unsigned short* __restrict__ xl,
    const unsigned short* __restrict__ wh, const unsigned short* __restrict__ wl,
    const float* __restrict__ bias, const float* __restrict__ pe_cos,
    const float* __restrict__ pe_sin, const float* __restrict__ pe_scale,
    unsigned short* __restrict__ qb, unsigned short* __restrict__ kb,
    unsigned short* __restrict__ vtb)
{
    __shared__ __align__(16) unsigned short Ah[128 * 32];
    __shared__ __align__(16) unsigned short Al[128 * 32];
    __shared__ __align__(16) unsigned short Bh[128 * 32];
    __shared__ __align__(16) unsigned short Bl[128 * 32];

    const int tid = threadIdx.x;
    const int w = tid >> 6, lane = tid & 63;
    const int g = lane >> 4, fr = lane & 15;
    const int wr = w >> 1, wc = w & 1;

    const int bid = blockIdx.x;                 // 1536 blocks, XCD swizzle
    const int s = (bid & 7) * 192 + (bid >> 3);
    const int m0 = (s & 63) * 128, n0 = (s >> 6) * 128;

    // staging: tile [128 r][32 k] bf16 = 512 x 16B chunks, linear LDS dest,
    // inverse-swizzled global source; swizzle swz(r) = ((r>>1)&3)<<4 bytes.
    const int c0 = tid, c1 = tid + 256;
    const int r0 = c0 >> 2, r1 = c1 >> 2;
    const int cb0 = ((c0 & 3) * 16) ^ (((r0 >> 1) & 3) << 4);
    const int cb1 = ((c1 & 3) * 16) ^ (((r1 >> 1) & 3) << 4);
    const unsigned short* pxh0 = xh + (size_t)(m0 + r0) * NC + (cb0 >> 1);
    const unsigned short* pxh1 = xh + (size_t)(m0 + r1) * NC + (cb1 >> 1);
    const unsigned short* pxl0 = xl + (size_t)(m0 + r0) * NC + (cb0 >> 1);
    const unsigned short* pxl1 = xl + (size_t)(m0 + r1) * NC + (cb1 >> 1);
    const unsigned short* pwh0 = wh + (size_t)(n0 + r0) * NC + (cb0 >> 1);
    const unsigned short* pwh1 = wh + (size_t)(n0 + r1) * NC + (cb1 >> 1);
    const unsigned short* pwl0 = wl + (size_t)(n0 + r0) * NC + (cb0 >> 1);
    const unsigned short* pwl1 = wl + (size_t)(n0 + r1) * NC + (cb1 >> 1);

    f32x4 acc[4][4];
#pragma unroll
    for (int m = 0; m < 4; ++m)
#pragma unroll
        for (int n = 0; n < 4; ++n) acc[m][n] = (f32x4){0.f, 0.f, 0.f, 0.f};

    for (int k0 = 0; k0 < NC; k0 += 32) {
        __syncthreads();
        GLL16(pxh0 + k0, (char*)Ah + c0 * 16);
        GLL16(pxh1 + k0, (char*)Ah + c1 * 16);
        GLL16(pxl0 + k0, (char*)Al + c0 * 16);
        GLL16(pxl1 + k0, (char*)Al + c1 * 16);
        GLL16(pwh0 + k0, (char*)Bh + c0 * 16);
        GLL16(pwh1 + k0, (char*)Bh + c1 * 16);
        GLL16(pwl0 + k0, (char*)Bl + c0 * 16);
        GLL16(pwl1 + k0, (char*)Bl + c1 * 16);
        __syncthreads();

        short8v a_h[4], a_l[4], b_h[4], b_l[4];
#pragma unroll
        for (int m = 0; m < 4; ++m) {
            const int r = wr * 64 + m * 16 + fr;
            const int off = r * 64 + ((g * 16) ^ (((r >> 1) & 3) << 4));
            a_h[m] = *(const short8v*)((const char*)Ah + off);
            a_l[m] = *(const short8v*)((const char*)Al + off);
        }
#pragma unroll
        for (int n = 0; n < 4; ++n) {
            const int r = wc * 64 + n * 16 + fr;
            const int off = r * 64 + ((g * 16) ^ (((r >> 1) & 3) << 4));
            b_h[n] = *(const short8v*)((const char*)Bh + off);
            b_l[n] = *(const short8v*)((const char*)Bl + off);
        }
#pragma unroll
        for (int m = 0; m < 4; ++m)
#pragma unroll
            for (int n = 0; n < 4; ++n) {
                acc[m][n] = __builtin_amdgcn_mfma_f32_16x16x32_bf16(a_h[m], b_h[n], acc[m][n], 0, 0, 0);
                acc[m][n] = __builtin_amdgcn_mfma_f32_16x16x32_bf16(a_h[m], b_l[n], acc[m][n], 0, 0, 0);
                acc[m][n] = __builtin_amdgcn_mfma_f32_16x16x32_bf16(a_l[m], b_h[n], acc[m][n], 0, 0, 0);
            }
    }

    // Epilogue: bias + RoPE (+*scale q, /scale k), scatter.
#pragma unroll
    for (int n = 0; n < 4; ++n) {
        const int col = n0 + wc * 64 + n * 16 + fr;
        const int part = col >> 10;             // wave-uniform (16-col span)
        const int hh = (col & 1023) >> 6;
        const int dd = col & 63;
        const float bv = bias[col];
#pragma unroll
        for (int m = 0; m < 4; ++m) {
            const int row0 = m0 + wr * 64 + m * 16 + 4 * g;  // j: row0..row0+3
            const int bb = row0 >> 11;
            const int t0 = row0 & 2047;
            if (part < 2) {
                unsigned short* outp = (part == 0) ? qb : kb;
#pragma unroll
                for (int j = 0; j < 4; ++j) {
                    const int t = t0 + j;
                    float val = acc[m][n][j] + bv;
                    const float partner = __shfl_xor(val, 1, 64);
                    const int pidx = t * HDIM + dd;
                    const float cc = pe_cos[pidx], ss = pe_sin[pidx], sc = pe_scale[pidx];
                    const float r = (dd & 1) ? (val * cc + partner * ss)
                                             : (val * cc - partner * ss);
                    val = (part == 0) ? (r * sc) : (r / sc);
                    outp[(((size_t)bb * NHEADS + hh) * NT + t) * HDIM + dd] = f2bf(val);
                }
            } else {
                // v transposed: vt[b][h][d][t], 4 consecutive t -> one 8B store
                ushort4 sv;
                sv.x = f2bf(acc[m][n][0] + bv);
                sv.y = f2bf(acc[m][n][1] + bv);
                sv.z = f2bf(acc[m][n][2] + bv);
                sv.w = f2bf(acc[m][n][3] + bv);
                *(ushort4*)&vtb[(((size_t)bb * NHEADS + hh) * HDIM + dd) * NT + t0] = sv;
            }
        }
    }
}

// ---------------------------------------------------------------------------
// Kernel 2: flash attention, bf16 MFMA. 1 block = (b,h,64 q-rows), 4 waves,
// each wave owns 16 q-rows. Q/K/Vt tiles row-XOR-swizzled in LDS; PV is
// structurally identical to QK^T (Vt pre-transposed by kernel 1).
// ---------------------------------------------------------------------------
__global__ __launch_bounds__(256) void attn_mfma_kernel(
    const unsigned short* __restrict__ qb, const unsigned short* __restrict__ kb,
    const unsigned short* __restrict__ vtb, const float* __restrict__ mask,
    float* __restrict__ out)
{
    __shared__ __align__(16) unsigned short Qs[64 * 64];
    __shared__ __align__(16) unsigned short Ks[64 * 64];
    __shared__ __align__(16) unsigned short Vs[64 * 64];
    __shared__ __align__(16) unsigned short Ps[4][16 * 64];

    const int tid = threadIdx.x;
    const int w = tid >> 6, lane = tid & 63;
    const int g = lane >> 4, fr = lane & 15;

    const int bid = blockIdx.x;                  // 2048 blocks, XCD swizzle
    const int s = (bid & 7) * 256 + (bid >> 3);
    const int q0 = (s & 31) * 64;
    const int h = (s >> 5) & 15;
    const int b = s >> 9;

    const size_t bh = (size_t)b * NHEADS + h;
    const unsigned short* qp = qb + (bh * NT + q0) * HDIM;
    const unsigned short* kp = kb + bh * NT * HDIM;
    const unsigned short* vtp = vtb + bh * HDIM * NT;
    const float* mp = mask + ((size_t)b * NT + q0) * NT;

    // stage Q: chunk c -> row r=c>>3 (q-row), swz(r)=(r&7)<<4 bytes
    {
        const int c0 = tid, c1 = tid + 256;
        const int r0 = c0 >> 3, cbq0 = ((c0 & 7) * 16) ^ ((r0 & 7) << 4);
        const int r1 = c1 >> 3, cbq1 = ((c1 & 7) * 16) ^ ((r1 & 7) << 4);
        GLL16(qp + r0 * HDIM + (cbq0 >> 1), (char*)Qs + c0 * 16);
        GLL16(qp + r1 * HDIM + (cbq1 >> 1), (char*)Qs + c1 * 16);
    }
    __syncthreads();
    short8v qf[2];
    {
        const int r = w * 16 + fr;
#pragma unroll
        for (int kk = 0; kk < 2; ++kk) {
            const int off = r * 128 + ((g * 16 + kk * 64) ^ ((r & 7) << 4));
            qf[kk] = *(const short8v*)((const char*)Qs + off);
        }
    }

    f32x4 acc[4];
    float li[4], mi[4];
#pragma unroll
    for (int j = 0; j < 4; ++j) {
        li[j] = 0.f; mi[j] = -3.0e38f;
        acc[j] = (f32x4){0.f, 0.f, 0.f, 0.f};
    }
    const float scl = 0.08838834764831845f;  // 1/sqrt(2*D)

    for (int kt = 0; kt < NT / 64; ++kt) {
        __syncthreads();
        {
            const unsigned short* ktp = kp + kt * 64 * HDIM;
#pragma unroll
            for (int half = 0; half < 2; ++half) {
                const int c = tid + half * 256;
                const int r = c >> 3;                       // K: key row; Vt: d row
                const int cb = ((c & 7) * 16) ^ ((r & 7) << 4);
                GLL16(ktp + r * HDIM + (cb >> 1), (char*)Ks + c * 16);
                GLL16(vtp + (size_t)r * NT + kt * 64 + (cb >> 1), (char*)Vs + c * 16);
            }
        }
        __syncthreads();

        // S = Q K^T  (S row = q-row w*16+4g+j, col = nt*16+fr)
        f32x4 S[4];
#pragma unroll
        for (int nt = 0; nt < 4; ++nt) {
            S[nt] = (f32x4){0.f, 0.f, 0.f, 0.f};
            const int r = nt * 16 + fr;
#pragma unroll
            for (int kk = 0; kk < 2; ++kk) {
                const int off = r * 128 + ((g * 16 + kk * 64) ^ ((r & 7) << 4));
                const short8v kf = *(const short8v*)((const char*)Ks + off);
                S[nt] = __builtin_amdgcn_mfma_f32_16x16x32_bf16(qf[kk], kf, S[nt], 0, 0, 0);
            }
        }

        // online softmax
#pragma unroll
        for (int j = 0; j < 4; ++j) {
            const int qrow = w * 16 + 4 * g + j;
            const float* mrow = mp + (size_t)qrow * NT + kt * 64 + fr;
            float sv[4];
            float rm = -3.4e38f;
#pragma unroll
            for (int nt = 0; nt < 4; ++nt) {
                sv[nt] = S[nt][j] * scl + mrow[nt * 16];
                rm = fmaxf(rm, sv[nt]);
            }
            rm = fmaxf(rm, __shfl_xor(rm, 1, 64));
            rm = fmaxf(rm, __shfl_xor(rm, 2, 64));
            rm = fmaxf(rm, __shfl_xor(rm, 4, 64));
            rm = fmaxf(rm, __shfl_xor(rm, 8, 64));
            const float mnew = fmaxf(mi[j], rm);
            const float alpha = __expf(mi[j] - mnew);
            float rs = 0.f;
            const int prow = 4 * g + j;
#pragma unroll
            for (int nt = 0; nt < 4; ++nt) {
                const float p = __expf(sv[nt] - mnew);
                const int off = prow * 128 + ((nt * 32 + fr * 2) ^ ((prow & 7) << 4));
                *(unsigned short*)((char*)Ps[w] + off) = f2bf(p);
                rs += p;
            }
            rs += __shfl_xor(rs, 1, 64);
            rs += __shfl_xor(rs, 2, 64);
            rs += __shfl_xor(rs, 4, 64);
            rs += __shfl_xor(rs, 8, 64);
            li[j] = li[j] * alpha + rs;
            mi[j] = mnew;
            acc[0][j] *= alpha; acc[1][j] *= alpha;
            acc[2][j] *= alpha; acc[3][j] *= alpha;
        }

        // PV: A = P (wave's 16x64, swizzled), B = Vt rows (d), same as QK^T
        short8v pf[2];
#pragma unroll
        for (int kk = 0; kk < 2; ++kk) {
            const int off = fr * 128 + ((g * 16 + kk * 64) ^ ((fr & 7) << 4));
            pf[kk] = *(const short8v*)((const char*)Ps[w] + off);
        }
#pragma unroll
        for (int dt = 0; dt < 4; ++dt) {
            const int d = dt * 16 + fr;
#pragma unroll
            for (int kk = 0; kk < 2; ++kk) {
                const int off = d * 128 + ((g * 16 + kk * 64) ^ ((d & 7) << 4));
                const short8v vf = *(const short8v*)((const char*)Vs + off);
                acc[dt] = __builtin_amdgcn_mfma_f32_16x16x32_bf16(pf[kk], vf, acc[dt], 0, 0, 0);
            }
        }
    }

    // epilogue: out[b][t][h][d] = acc / l, layout (B,T,NH,D), fp32
#pragma unroll
    for (int j = 0; j < 4; ++j) {
        const float inv = 1.f / li[j];
        const int t = q0 + w * 16 + 4 * g + j;
        float* op = out + (((size_t)b * NT + t) * NHEADS + h) * HDIM;
#pragma unroll
        for (int dt = 0; dt < 4; ++dt) op[dt * 16 + fr] = acc[dt][j] * inv;
    }
}

extern "C" void kernel_launch(void* const* d_in, const int* in_sizes, int n_in,
                              void* d_out, int out_size, void* d_ws, size_t ws_size,
                              hipStream_t stream) {
    const float* x        = (const float*)d_in[0];
    const float* pe_cos   = (const float*)d_in[1];
    const float* pe_sin   = (const float*)d_in[2];
    const float* pe_scale = (const float*)d_in[3];
    const float* mask     = (const float*)d_in[4];
    const float* w_qkv    = (const float*)d_in[5];
    const float* b_qkv    = (const float*)d_in[6];
    float* out = (float*)d_out;

    unsigned short* ws = (unsigned short*)d_ws;
    const size_t PER = (size_t)NB * NHEADS * NT * HDIM;   // 8388608
    unsigned short* qbuf = ws;
    unsigned short* kbuf = ws + PER;
    unsigned short* vtbuf = ws + 2 * PER;
    unsigned short* xh = ws + 3 * PER;
    unsigned short* xl = ws + 4 * PER;
    unsigned short* whi = ws + 5 * PER;
    unsigned short* wlo = whi + (size_t)3 * NC * NC;

    split_bf16_kernel<<<8192, 256, 0, stream>>>(x, xh, xl, (NB * NT * NC) / 4);
    split_bf16_kernel<<<3072, 256, 0, stream>>>(w_qkv, whi, wlo, (3 * NC * NC) / 4);
    qkv_gemm_kernel<<<1536, 256, 0, stream>>>(xh, xl, whi, wlo, b_qkv,
                                              pe_cos, pe_sin, pe_scale,
                                              qbuf, kbuf, vtbuf);
    attn_mfma_kernel<<<2048, 256, 0, stream>>>(qbuf, kbuf, vtbuf, mask, out);
}

// Round 4
// 385.796 us; speedup vs baseline: 12.5830x; 1.1568x over previous
//
#include <hip/hip_runtime.h>
#include <math.h>

#define NB 4
#define NT 2048
#define NC 1024
#define NHEADS 16
#define HDIM 64

typedef __attribute__((ext_vector_type(8))) short short8v;
typedef __attribute__((ext_vector_type(4))) float f32x4;

__device__ inline unsigned short f2bf(float f) {
    unsigned int u = __float_as_uint(f);
    u += 0x7FFFu + ((u >> 16) & 1u);
    return (unsigned short)(u >> 16);
}
__device__ inline float bf2f(unsigned short h) {
    return __uint_as_float(((unsigned int)h) << 16);
}

#define AS1C(p) ((const __attribute__((address_space(1))) unsigned int*)(unsigned long long)(const void*)(p))
#define AS3P(p) ((__attribute__((address_space(3))) unsigned int*)(unsigned int)(unsigned long long)(void*)(p))
#define GLL16(gp, lp) __builtin_amdgcn_global_load_lds(AS1C(gp), AS3P(lp), 16, 0, 0)

// ---------------------------------------------------------------------------
// split fp32 -> bf16 hi + bf16 lo
// ---------------------------------------------------------------------------
__global__ __launch_bounds__(256) void split_bf16_kernel(
    const float* __restrict__ in, unsigned short* __restrict__ hi,
    unsigned short* __restrict__ lo, int n4)
{
    const int i = blockIdx.x * 256 + threadIdx.x;
    if (i >= n4) return;
    const float4 f = ((const float4*)in)[i];
    ushort4 h, l;
    h.x = f2bf(f.x); l.x = f2bf(f.x - bf2f(h.x));
    h.y = f2bf(f.y); l.y = f2bf(f.y - bf2f(h.y));
    h.z = f2bf(f.z); l.z = f2bf(f.z - bf2f(h.z));
    h.w = f2bf(f.w); l.w = f2bf(f.w - bf2f(h.w));
    ((ushort4*)hi)[i] = h;
    ((ushort4*)lo)[i] = l;
}

// ---------------------------------------------------------------------------
// Kernel 1: qkv = x @ w^T + b via split-bf16 MFMA (AhBh + AhBl + AlBh),
// fused RoPE epilogue. q,k written bf16 (B,NH,T,D); v written TRANSPOSED
// bf16 (B,NH,D,T) so attention's PV B-operand reads are linear.
// M=8192, N=3072, K=1024. Tile 128x128x32, 4 waves, 64x64 per wave.
// ---------------------------------------------------------------------------
__global__ __launch_bounds__(256) void qkv_gemm_kernel(
    const unsigned short* __restrict__ xh, const unsigned short* __restrict__ xl,
    const unsigned short* __restrict__ wh, const unsigned short* __restrict__ wl,
    const float* __restrict__ bias, const float* __restrict__ pe_cos,
    const float* __restrict__ pe_sin, const float* __restrict__ pe_scale,
    unsigned short* __restrict__ qb, unsigned short* __restrict__ kb,
    unsigned short* __restrict__ vtb)
{
    __shared__ __align__(16) unsigned short Ah[128 * 32];
    __shared__ __align__(16) unsigned short Al[128 * 32];
    __shared__ __align__(16) unsigned short Bh[128 * 32];
    __shared__ __align__(16) unsigned short Bl[128 * 32];

    const int tid = threadIdx.x;
    const int w = tid >> 6, lane = tid & 63;
    const int g = lane >> 4, fr = lane & 15;
    const int wr = w >> 1, wc = w & 1;

    const int bid = blockIdx.x;                 // 1536 blocks, XCD swizzle
    const int s = (bid & 7) * 192 + (bid >> 3);
    const int m0 = (s & 63) * 128, n0 = (s >> 6) * 128;

    // staging: tile [128 r][32 k] bf16 = 512 x 16B chunks, linear LDS dest,
    // inverse-swizzled global source; swizzle swz(r) = ((r>>1)&3)<<4 bytes.
    const int c0 = tid, c1 = tid + 256;
    const int r0 = c0 >> 2, r1 = c1 >> 2;
    const int cb0 = ((c0 & 3) * 16) ^ (((r0 >> 1) & 3) << 4);
    const int cb1 = ((c1 & 3) * 16) ^ (((r1 >> 1) & 3) << 4);
    const unsigned short* pxh0 = xh + (size_t)(m0 + r0) * NC + (cb0 >> 1);
    const unsigned short* pxh1 = xh + (size_t)(m0 + r1) * NC + (cb1 >> 1);
    const unsigned short* pxl0 = xl + (size_t)(m0 + r0) * NC + (cb0 >> 1);
    const unsigned short* pxl1 = xl + (size_t)(m0 + r1) * NC + (cb1 >> 1);
    const unsigned short* pwh0 = wh + (size_t)(n0 + r0) * NC + (cb0 >> 1);
    const unsigned short* pwh1 = wh + (size_t)(n0 + r1) * NC + (cb1 >> 1);
    const unsigned short* pwl0 = wl + (size_t)(n0 + r0) * NC + (cb0 >> 1);
    const unsigned short* pwl1 = wl + (size_t)(n0 + r1) * NC + (cb1 >> 1);

    f32x4 acc[4][4];
#pragma unroll
    for (int m = 0; m < 4; ++m)
#pragma unroll
        for (int n = 0; n < 4; ++n) acc[m][n] = (f32x4){0.f, 0.f, 0.f, 0.f};

    for (int k0 = 0; k0 < NC; k0 += 32) {
        __syncthreads();
        GLL16(pxh0 + k0, (char*)Ah + c0 * 16);
        GLL16(pxh1 + k0, (char*)Ah + c1 * 16);
        GLL16(pxl0 + k0, (char*)Al + c0 * 16);
        GLL16(pxl1 + k0, (char*)Al + c1 * 16);
        GLL16(pwh0 + k0, (char*)Bh + c0 * 16);
        GLL16(pwh1 + k0, (char*)Bh + c1 * 16);
        GLL16(pwl0 + k0, (char*)Bl + c0 * 16);
        GLL16(pwl1 + k0, (char*)Bl + c1 * 16);
        __syncthreads();

        short8v a_h[4], a_l[4], b_h[4], b_l[4];
#pragma unroll
        for (int m = 0; m < 4; ++m) {
            const int r = wr * 64 + m * 16 + fr;
            const int off = r * 64 + ((g * 16) ^ (((r >> 1) & 3) << 4));
            a_h[m] = *(const short8v*)((const char*)Ah + off);
            a_l[m] = *(const short8v*)((const char*)Al + off);
        }
#pragma unroll
        for (int n = 0; n < 4; ++n) {
            const int r = wc * 64 + n * 16 + fr;
            const int off = r * 64 + ((g * 16) ^ (((r >> 1) & 3) << 4));
            b_h[n] = *(const short8v*)((const char*)Bh + off);
            b_l[n] = *(const short8v*)((const char*)Bl + off);
        }
#pragma unroll
        for (int m = 0; m < 4; ++m)
#pragma unroll
            for (int n = 0; n < 4; ++n) {
                acc[m][n] = __builtin_amdgcn_mfma_f32_16x16x32_bf16(a_h[m], b_h[n], acc[m][n], 0, 0, 0);
                acc[m][n] = __builtin_amdgcn_mfma_f32_16x16x32_bf16(a_h[m], b_l[n], acc[m][n], 0, 0, 0);
                acc[m][n] = __builtin_amdgcn_mfma_f32_16x16x32_bf16(a_l[m], b_h[n], acc[m][n], 0, 0, 0);
            }
    }

    // Epilogue: bias + RoPE (+*scale q, /scale k), scatter.
#pragma unroll
    for (int n = 0; n < 4; ++n) {
        const int col = n0 + wc * 64 + n * 16 + fr;
        const int part = col >> 10;             // wave-uniform (16-col span)
        const int hh = (col & 1023) >> 6;
        const int dd = col & 63;
        const float bv = bias[col];
#pragma unroll
        for (int m = 0; m < 4; ++m) {
            const int row0 = m0 + wr * 64 + m * 16 + 4 * g;  // j: row0..row0+3
            const int bb = row0 >> 11;
            const int t0 = row0 & 2047;
            if (part < 2) {
                unsigned short* outp = (part == 0) ? qb : kb;
#pragma unroll
                for (int j = 0; j < 4; ++j) {
                    const int t = t0 + j;
                    float val = acc[m][n][j] + bv;
                    const float partner = __shfl_xor(val, 1, 64);
                    const int pidx = t * HDIM + dd;
                    const float cc = pe_cos[pidx], ss = pe_sin[pidx], sc = pe_scale[pidx];
                    const float r = (dd & 1) ? (val * cc + partner * ss)
                                             : (val * cc - partner * ss);
                    val = (part == 0) ? (r * sc) : (r / sc);
                    outp[(((size_t)bb * NHEADS + hh) * NT + t) * HDIM + dd] = f2bf(val);
                }
            } else {
                // v transposed: vt[b][h][d][t], 4 consecutive t -> one 8B store
                ushort4 sv;
                sv.x = f2bf(acc[m][n][0] + bv);
                sv.y = f2bf(acc[m][n][1] + bv);
                sv.z = f2bf(acc[m][n][2] + bv);
                sv.w = f2bf(acc[m][n][3] + bv);
                *(ushort4*)&vtb[(((size_t)bb * NHEADS + hh) * HDIM + dd) * NT + t0] = sv;
            }
        }
    }
}

// ---------------------------------------------------------------------------
// Kernel 2: flash attention, bf16 MFMA. 1 block = (b,h,64 q-rows), 4 waves,
// each wave owns 16 q-rows. Q/K/Vt tiles row-XOR-swizzled in LDS.
// Defer-max softmax (T13): mi updated via cross-lane reduce only when a tile
// threatens exp overflow (threshold 8); li kept per-lane partial, reduced
// once after the kt loop. Common path has ZERO shuffles.
// ---------------------------------------------------------------------------
__global__ __launch_bounds__(256) void attn_mfma_kernel(
    const unsigned short* __restrict__ qb, const unsigned short* __restrict__ kb,
    const unsigned short* __restrict__ vtb, const float* __restrict__ mask,
    float* __restrict__ out)
{
    __shared__ __align__(16) unsigned short Qs[64 * 64];
    __shared__ __align__(16) unsigned short Ks[64 * 64];
    __shared__ __align__(16) unsigned short Vs[64 * 64];
    __shared__ __align__(16) unsigned short Ps[4][16 * 64];

    const int tid = threadIdx.x;
    const int w = tid >> 6, lane = tid & 63;
    const int g = lane >> 4, fr = lane & 15;

    const int bid = blockIdx.x;                  // 2048 blocks, XCD swizzle
    const int s = (bid & 7) * 256 + (bid >> 3);
    const int q0 = (s & 31) * 64;
    const int h = (s >> 5) & 15;
    const int b = s >> 9;

    const size_t bh = (size_t)b * NHEADS + h;
    const unsigned short* qp = qb + (bh * NT + q0) * HDIM;
    const unsigned short* kp = kb + bh * NT * HDIM;
    const unsigned short* vtp = vtb + bh * HDIM * NT;
    const float* mp = mask + ((size_t)b * NT + q0) * NT;

    // stage Q: chunk c -> row r=c>>3 (q-row), swz(r)=(r&7)<<4 bytes
    {
        const int c0 = tid, c1 = tid + 256;
        const int r0 = c0 >> 3, cbq0 = ((c0 & 7) * 16) ^ ((r0 & 7) << 4);
        const int r1 = c1 >> 3, cbq1 = ((c1 & 7) * 16) ^ ((r1 & 7) << 4);
        GLL16(qp + r0 * HDIM + (cbq0 >> 1), (char*)Qs + c0 * 16);
        GLL16(qp + r1 * HDIM + (cbq1 >> 1), (char*)Qs + c1 * 16);
    }
    __syncthreads();
    short8v qf[2];
    {
        const int r = w * 16 + fr;
#pragma unroll
        for (int kk = 0; kk < 2; ++kk) {
            const int off = r * 128 + ((g * 16 + kk * 64) ^ ((r & 7) << 4));
            qf[kk] = *(const short8v*)((const char*)Qs + off);
        }
    }

    f32x4 acc[4];
    float li[4], mi[4];
#pragma unroll
    for (int j = 0; j < 4; ++j) {
        li[j] = 0.f; mi[j] = -3.0e38f;
        acc[j] = (f32x4){0.f, 0.f, 0.f, 0.f};
    }
    const float scl = 0.08838834764831845f;  // 1/sqrt(2*D)

    for (int kt = 0; kt < NT / 64; ++kt) {
        __syncthreads();
        {
            const unsigned short* ktp = kp + kt * 64 * HDIM;
#pragma unroll
            for (int half = 0; half < 2; ++half) {
                const int c = tid + half * 256;
                const int r = c >> 3;                       // K: key row; Vt: d row
                const int cb = ((c & 7) * 16) ^ ((r & 7) << 4);
                GLL16(ktp + r * HDIM + (cb >> 1), (char*)Ks + c * 16);
                GLL16(vtp + (size_t)r * NT + kt * 64 + (cb >> 1), (char*)Vs + c * 16);
            }
        }
        __syncthreads();

        // S = Q K^T  (S row = q-row w*16+4g+j, col = nt*16+fr)
        f32x4 S[4];
#pragma unroll
        for (int nt = 0; nt < 4; ++nt) {
            S[nt] = (f32x4){0.f, 0.f, 0.f, 0.f};
            const int r = nt * 16 + fr;
#pragma unroll
            for (int kk = 0; kk < 2; ++kk) {
                const int off = r * 128 + ((g * 16 + kk * 64) ^ ((r & 7) << 4));
                const short8v kf = *(const short8v*)((const char*)Ks + off);
                S[nt] = __builtin_amdgcn_mfma_f32_16x16x32_bf16(qf[kk], kf, S[nt], 0, 0, 0);
            }
        }

        // scale + mask; in-lane row max estimate (no cross-lane in common path)
        float sv[4][4], rmj[4];
#pragma unroll
        for (int j = 0; j < 4; ++j) {
            const int qrow = w * 16 + 4 * g + j;
            const float* mrow = mp + (size_t)qrow * NT + kt * 64 + fr;
#pragma unroll
            for (int nt = 0; nt < 4; ++nt)
                sv[j][nt] = fmaf(S[nt][j], scl, mrow[nt * 16]);
            rmj[j] = fmaxf(fmaxf(sv[j][0], sv[j][1]), fmaxf(sv[j][2], sv[j][3]));
        }

        // defer-max: only reduce + rescale when some lane exceeds mi+8
        float worst = fmaxf(fmaxf(rmj[0] - mi[0], rmj[1] - mi[1]),
                            fmaxf(rmj[2] - mi[2], rmj[3] - mi[3]));
        if (!__all(worst <= 8.f)) {
#pragma unroll
            for (int j = 0; j < 4; ++j) {
                float rm = rmj[j];
                rm = fmaxf(rm, __shfl_xor(rm, 1, 64));
                rm = fmaxf(rm, __shfl_xor(rm, 2, 64));
                rm = fmaxf(rm, __shfl_xor(rm, 4, 64));
                rm = fmaxf(rm, __shfl_xor(rm, 8, 64));
                const float mnew = fmaxf(mi[j], rm);
                const float alpha = __expf(mi[j] - mnew);
                li[j] *= alpha;
                acc[0][j] *= alpha; acc[1][j] *= alpha;
                acc[2][j] *= alpha; acc[3][j] *= alpha;
                mi[j] = mnew;
            }
        }

        // P = exp(sv - mi) (bounded by e^8); per-lane partial li; store P
#pragma unroll
        for (int j = 0; j < 4; ++j) {
            const int prow = 4 * g + j;
            float ps = 0.f;
#pragma unroll
            for (int nt = 0; nt < 4; ++nt) {
                const float p = __expf(sv[j][nt] - mi[j]);
                const int off = prow * 128 + ((nt * 32 + fr * 2) ^ ((prow & 7) << 4));
                *(unsigned short*)((char*)Ps[w] + off) = f2bf(p);
                ps += p;
            }
            li[j] += ps;
        }

        // PV: A = P (wave's 16x64, swizzled), B = Vt rows (d), same as QK^T
        short8v pf[2];
#pragma unroll
        for (int kk = 0; kk < 2; ++kk) {
            const int off = fr * 128 + ((g * 16 + kk * 64) ^ ((fr & 7) << 4));
            pf[kk] = *(const short8v*)((const char*)Ps[w] + off);
        }
#pragma unroll
        for (int dt = 0; dt < 4; ++dt) {
            const int d = dt * 16 + fr;
#pragma unroll
            for (int kk = 0; kk < 2; ++kk) {
                const int off = d * 128 + ((g * 16 + kk * 64) ^ ((d & 7) << 4));
                const short8v vf = *(const short8v*)((const char*)Vs + off);
                acc[dt] = __builtin_amdgcn_mfma_f32_16x16x32_bf16(pf[kk], vf, acc[dt], 0, 0, 0);
            }
        }
    }

    // final cross-lane li reduce (once), then epilogue
#pragma unroll
    for (int j = 0; j < 4; ++j) {
        float lt = li[j];
        lt += __shfl_xor(lt, 1, 64);
        lt += __shfl_xor(lt, 2, 64);
        lt += __shfl_xor(lt, 4, 64);
        lt += __shfl_xor(lt, 8, 64);
        const float inv = 1.f / lt;
        const int t = q0 + w * 16 + 4 * g + j;
        float* op = out + (((size_t)b * NT + t) * NHEADS + h) * HDIM;
#pragma unroll
        for (int dt = 0; dt < 4; ++dt) op[dt * 16 + fr] = acc[dt][j] * inv;
    }
}

extern "C" void kernel_launch(void* const* d_in, const int* in_sizes, int n_in,
                              void* d_out, int out_size, void* d_ws, size_t ws_size,
                              hipStream_t stream) {
    const float* x        = (const float*)d_in[0];
    const float* pe_cos   = (const float*)d_in[1];
    const float* pe_sin   = (const float*)d_in[2];
    const float* pe_scale = (const float*)d_in[3];
    const float* mask     = (const float*)d_in[4];
    const float* w_qkv    = (const float*)d_in[5];
    const float* b_qkv    = (const float*)d_in[6];
    float* out = (float*)d_out;

    unsigned short* ws = (unsigned short*)d_ws;
    const size_t PER = (size_t)NB * NHEADS * NT * HDIM;   // 8388608
    unsigned short* qbuf = ws;
    unsigned short* kbuf = ws + PER;
    unsigned short* vtbuf = ws + 2 * PER;
    unsigned short* xh = ws + 3 * PER;
    unsigned short* xl = ws + 4 * PER;
    unsigned short* whi = ws + 5 * PER;
    unsigned short* wlo = whi + (size_t)3 * NC * NC;

    split_bf16_kernel<<<8192, 256, 0, stream>>>(x, xh, xl, (NB * NT * NC) / 4);
    split_bf16_kernel<<<3072, 256, 0, stream>>>(w_qkv, whi, wlo, (3 * NC * NC) / 4);
    qkv_gemm_kernel<<<1536, 256, 0, stream>>>(xh, xl, whi, wlo, b_qkv,
                                              pe_cos, pe_sin, pe_scale,
                                              qbuf, kbuf, vtbuf);
    attn_mfma_kernel<<<2048, 256, 0, stream>>>(qbuf, kbuf, vtbuf, mask, out);
}

// Round 5
// 277.170 us; speedup vs baseline: 17.5145x; 1.3919x over previous
//
#include <hip/hip_runtime.h>
#include <math.h>

#define NB 4
#define NT 2048
#define NC 1024
#define NHEADS 16
#define HDIM 64

typedef __attribute__((ext_vector_type(8))) _Float16 half8v;
typedef __attribute__((ext_vector_type(4))) float f32x4;

__device__ inline unsigned short f2h(float f) {
    _Float16 h = (_Float16)f;
    return __builtin_bit_cast(unsigned short, h);
}

#define AS1C(p) ((const __attribute__((address_space(1))) unsigned int*)(unsigned long long)(const void*)(p))
#define AS3P(p) ((__attribute__((address_space(3))) unsigned int*)(unsigned int)(unsigned long long)(void*)(p))
#define GLL16(gp, lp) __builtin_amdgcn_global_load_lds(AS1C(gp), AS3P(lp), 16, 0, 0)

// ---------------------------------------------------------------------------
// fp32 -> fp16 convert (vectorized)
// ---------------------------------------------------------------------------
__global__ __launch_bounds__(256) void conv_f16_kernel(
    const float* __restrict__ in, unsigned short* __restrict__ out, int n4)
{
    const int i = blockIdx.x * 256 + threadIdx.x;
    if (i >= n4) return;
    const float4 f = ((const float4*)in)[i];
    ushort4 h;
    h.x = f2h(f.x); h.y = f2h(f.y); h.z = f2h(f.z); h.w = f2h(f.w);
    ((ushort4*)out)[i] = h;
}

// ---------------------------------------------------------------------------
// Kernel 1: qkv = x @ w^T + b via fp16 MFMA (single product), fused RoPE.
// q,k written fp16 (B,NH,T,D); v written TRANSPOSED fp16 (B,NH,D,T).
// M=8192, N=3072, K=1024. Tile 128x128x32, 4 waves, 64x64 per wave.
// LDS addressing byte-identical to the verified round-3 structure.
// ---------------------------------------------------------------------------
__global__ __launch_bounds__(256) void qkv_gemm_kernel(
    const unsigned short* __restrict__ xf, const unsigned short* __restrict__ wf,
    const float* __restrict__ bias, const float* __restrict__ pe_cos,
    const float* __restrict__ pe_sin, const float* __restrict__ pe_scale,
    unsigned short* __restrict__ qb, unsigned short* __restrict__ kb,
    unsigned short* __restrict__ vtb)
{
    __shared__ __align__(16) unsigned short Ah[128 * 32];
    __shared__ __align__(16) unsigned short Bh[128 * 32];

    const int tid = threadIdx.x;
    const int w = tid >> 6, lane = tid & 63;
    const int g = lane >> 4, fr = lane & 15;
    const int wr = w >> 1, wc = w & 1;

    const int bid = blockIdx.x;                 // 1536 blocks, XCD swizzle
    const int s = (bid & 7) * 192 + (bid >> 3);
    const int m0 = (s & 63) * 128, n0 = (s >> 6) * 128;

    // staging: tile [128 r][32 k] fp16 = 512 x 16B chunks, linear LDS dest,
    // inverse-swizzled global source; swz(r) = ((r>>1)&3)<<4 bytes.
    const int c0 = tid, c1 = tid + 256;
    const int r0 = c0 >> 2, r1 = c1 >> 2;
    const int cb0 = ((c0 & 3) * 16) ^ (((r0 >> 1) & 3) << 4);
    const int cb1 = ((c1 & 3) * 16) ^ (((r1 >> 1) & 3) << 4);
    const unsigned short* px0 = xf + (size_t)(m0 + r0) * NC + (cb0 >> 1);
    const unsigned short* px1 = xf + (size_t)(m0 + r1) * NC + (cb1 >> 1);
    const unsigned short* pw0 = wf + (size_t)(n0 + r0) * NC + (cb0 >> 1);
    const unsigned short* pw1 = wf + (size_t)(n0 + r1) * NC + (cb1 >> 1);

    f32x4 acc[4][4];
#pragma unroll
    for (int m = 0; m < 4; ++m)
#pragma unroll
        for (int n = 0; n < 4; ++n) acc[m][n] = (f32x4){0.f, 0.f, 0.f, 0.f};

    for (int k0 = 0; k0 < NC; k0 += 32) {
        __syncthreads();
        GLL16(px0 + k0, (char*)Ah + c0 * 16);
        GLL16(px1 + k0, (char*)Ah + c1 * 16);
        GLL16(pw0 + k0, (char*)Bh + c0 * 16);
        GLL16(pw1 + k0, (char*)Bh + c1 * 16);
        __syncthreads();

        half8v a_f[4], b_f[4];
#pragma unroll
        for (int m = 0; m < 4; ++m) {
            const int r = wr * 64 + m * 16 + fr;
            const int off = r * 64 + ((g * 16) ^ (((r >> 1) & 3) << 4));
            a_f[m] = *(const half8v*)((const char*)Ah + off);
        }
#pragma unroll
        for (int n = 0; n < 4; ++n) {
            const int r = wc * 64 + n * 16 + fr;
            const int off = r * 64 + ((g * 16) ^ (((r >> 1) & 3) << 4));
            b_f[n] = *(const half8v*)((const char*)Bh + off);
        }
#pragma unroll
        for (int m = 0; m < 4; ++m)
#pragma unroll
            for (int n = 0; n < 4; ++n)
                acc[m][n] = __builtin_amdgcn_mfma_f32_16x16x32_f16(a_f[m], b_f[n], acc[m][n], 0, 0, 0);
    }

    // Epilogue: bias + RoPE (+*scale q, /scale k), scatter.
#pragma unroll
    for (int n = 0; n < 4; ++n) {
        const int col = n0 + wc * 64 + n * 16 + fr;
        const int part = col >> 10;             // wave-uniform (16-col span)
        const int hh = (col & 1023) >> 6;
        const int dd = col & 63;
        const float bv = bias[col];
#pragma unroll
        for (int m = 0; m < 4; ++m) {
            const int row0 = m0 + wr * 64 + m * 16 + 4 * g;  // j: row0..row0+3
            const int bb = row0 >> 11;
            const int t0 = row0 & 2047;
            if (part < 2) {
                unsigned short* outp = (part == 0) ? qb : kb;
#pragma unroll
                for (int j = 0; j < 4; ++j) {
                    const int t = t0 + j;
                    float val = acc[m][n][j] + bv;
                    const float partner = __shfl_xor(val, 1, 64);
                    const int pidx = t * HDIM + dd;
                    const float cc = pe_cos[pidx], ss = pe_sin[pidx], sc = pe_scale[pidx];
                    const float r = (dd & 1) ? (val * cc + partner * ss)
                                             : (val * cc - partner * ss);
                    val = (part == 0) ? (r * sc) : (r / sc);
                    outp[(((size_t)bb * NHEADS + hh) * NT + t) * HDIM + dd] = f2h(val);
                }
            } else {
                // v transposed: vt[b][h][d][t], 4 consecutive t -> one 8B store
                ushort4 sv;
                sv.x = f2h(acc[m][n][0] + bv);
                sv.y = f2h(acc[m][n][1] + bv);
                sv.z = f2h(acc[m][n][2] + bv);
                sv.w = f2h(acc[m][n][3] + bv);
                *(ushort4*)&vtb[(((size_t)bb * NHEADS + hh) * HDIM + dd) * NT + t0] = sv;
            }
        }
    }
}

// ---------------------------------------------------------------------------
// Kernel 2: flash attention, fp16 MFMA. 1 block = (b,h,64 q-rows), 4 waves,
// each wave owns 16 q-rows. Q/K/Vt tiles row-XOR-swizzled in LDS.
// Defer-max softmax (T13); li per-lane partial, reduced once at the end.
// ---------------------------------------------------------------------------
__global__ __launch_bounds__(256) void attn_mfma_kernel(
    const unsigned short* __restrict__ qb, const unsigned short* __restrict__ kb,
    const unsigned short* __restrict__ vtb, const float* __restrict__ mask,
    float* __restrict__ out)
{
    __shared__ __align__(16) unsigned short Qs[64 * 64];
    __shared__ __align__(16) unsigned short Ks[64 * 64];
    __shared__ __align__(16) unsigned short Vs[64 * 64];
    __shared__ __align__(16) unsigned short Ps[4][16 * 64];

    const int tid = threadIdx.x;
    const int w = tid >> 6, lane = tid & 63;
    const int g = lane >> 4, fr = lane & 15;

    const int bid = blockIdx.x;                  // 2048 blocks, XCD swizzle
    const int s = (bid & 7) * 256 + (bid >> 3);
    const int q0 = (s & 31) * 64;
    const int h = (s >> 5) & 15;
    const int b = s >> 9;

    const size_t bh = (size_t)b * NHEADS + h;
    const unsigned short* qp = qb + (bh * NT + q0) * HDIM;
    const unsigned short* kp = kb + bh * NT * HDIM;
    const unsigned short* vtp = vtb + bh * HDIM * NT;
    const float* mp = mask + ((size_t)b * NT + q0) * NT;

    // stage Q: chunk c -> row r=c>>3 (q-row), swz(r)=(r&7)<<4 bytes
    {
        const int c0 = tid, c1 = tid + 256;
        const int r0 = c0 >> 3, cbq0 = ((c0 & 7) * 16) ^ ((r0 & 7) << 4);
        const int r1 = c1 >> 3, cbq1 = ((c1 & 7) * 16) ^ ((r1 & 7) << 4);
        GLL16(qp + r0 * HDIM + (cbq0 >> 1), (char*)Qs + c0 * 16);
        GLL16(qp + r1 * HDIM + (cbq1 >> 1), (char*)Qs + c1 * 16);
    }
    __syncthreads();
    half8v qf[2];
    {
        const int r = w * 16 + fr;
#pragma unroll
        for (int kk = 0; kk < 2; ++kk) {
            const int off = r * 128 + ((g * 16 + kk * 64) ^ ((r & 7) << 4));
            qf[kk] = *(const half8v*)((const char*)Qs + off);
        }
    }

    f32x4 acc[4];
    float li[4], mi[4];
#pragma unroll
    for (int j = 0; j < 4; ++j) {
        li[j] = 0.f; mi[j] = -3.0e38f;
        acc[j] = (f32x4){0.f, 0.f, 0.f, 0.f};
    }
    const float scl = 0.08838834764831845f;  // 1/sqrt(2*D)

    for (int kt = 0; kt < NT / 64; ++kt) {
        __syncthreads();
        {
            const unsigned short* ktp = kp + kt * 64 * HDIM;
#pragma unroll
            for (int half = 0; half < 2; ++half) {
                const int c = tid + half * 256;
                const int r = c >> 3;                       // K: key row; Vt: d row
                const int cb = ((c & 7) * 16) ^ ((r & 7) << 4);
                GLL16(ktp + r * HDIM + (cb >> 1), (char*)Ks + c * 16);
                GLL16(vtp + (size_t)r * NT + kt * 64 + (cb >> 1), (char*)Vs + c * 16);
            }
        }
        __syncthreads();

        // S = Q K^T  (S row = q-row w*16+4g+j, col = nt*16+fr)
        f32x4 S[4];
#pragma unroll
        for (int nt = 0; nt < 4; ++nt) {
            S[nt] = (f32x4){0.f, 0.f, 0.f, 0.f};
            const int r = nt * 16 + fr;
#pragma unroll
            for (int kk = 0; kk < 2; ++kk) {
                const int off = r * 128 + ((g * 16 + kk * 64) ^ ((r & 7) << 4));
                const half8v kf = *(const half8v*)((const char*)Ks + off);
                S[nt] = __builtin_amdgcn_mfma_f32_16x16x32_f16(qf[kk], kf, S[nt], 0, 0, 0);
            }
        }

        // scale + mask; in-lane row max estimate (no cross-lane in common path)
        float sv[4][4], rmj[4];
#pragma unroll
        for (int j = 0; j < 4; ++j) {
            const int qrow = w * 16 + 4 * g + j;
            const float* mrow = mp + (size_t)qrow * NT + kt * 64 + fr;
#pragma unroll
            for (int nt = 0; nt < 4; ++nt)
                sv[j][nt] = fmaf(S[nt][j], scl, mrow[nt * 16]);
            rmj[j] = fmaxf(fmaxf(sv[j][0], sv[j][1]), fmaxf(sv[j][2], sv[j][3]));
        }

        // defer-max: only reduce + rescale when some lane exceeds mi+8
        float worst = fmaxf(fmaxf(rmj[0] - mi[0], rmj[1] - mi[1]),
                            fmaxf(rmj[2] - mi[2], rmj[3] - mi[3]));
        if (!__all(worst <= 8.f)) {
#pragma unroll
            for (int j = 0; j < 4; ++j) {
                float rm = rmj[j];
                rm = fmaxf(rm, __shfl_xor(rm, 1, 64));
                rm = fmaxf(rm, __shfl_xor(rm, 2, 64));
                rm = fmaxf(rm, __shfl_xor(rm, 4, 64));
                rm = fmaxf(rm, __shfl_xor(rm, 8, 64));
                const float mnew = fmaxf(mi[j], rm);
                const float alpha = __expf(mi[j] - mnew);
                li[j] *= alpha;
                acc[0][j] *= alpha; acc[1][j] *= alpha;
                acc[2][j] *= alpha; acc[3][j] *= alpha;
                mi[j] = mnew;
            }
        }

        // P = exp(sv - mi) (bounded by e^8); per-lane partial li; store P fp16
#pragma unroll
        for (int j = 0; j < 4; ++j) {
            const int prow = 4 * g + j;
            float ps = 0.f;
#pragma unroll
            for (int nt = 0; nt < 4; ++nt) {
                const float p = __expf(sv[j][nt] - mi[j]);
                const int off = prow * 128 + ((nt * 32 + fr * 2) ^ ((prow & 7) << 4));
                *(unsigned short*)((char*)Ps[w] + off) = f2h(p);
                ps += p;
            }
            li[j] += ps;
        }

        // PV: A = P (wave's 16x64, swizzled), B = Vt rows (d), same as QK^T
        half8v pf[2];
#pragma unroll
        for (int kk = 0; kk < 2; ++kk) {
            const int off = fr * 128 + ((g * 16 + kk * 64) ^ ((fr & 7) << 4));
            pf[kk] = *(const half8v*)((const char*)Ps[w] + off);
        }
#pragma unroll
        for (int dt = 0; dt < 4; ++dt) {
            const int d = dt * 16 + fr;
#pragma unroll
            for (int kk = 0; kk < 2; ++kk) {
                const int off = d * 128 + ((g * 16 + kk * 64) ^ ((d & 7) << 4));
                const half8v vf = *(const half8v*)((const char*)Vs + off);
                acc[dt] = __builtin_amdgcn_mfma_f32_16x16x32_f16(pf[kk], vf, acc[dt], 0, 0, 0);
            }
        }
    }

    // final cross-lane li reduce (once), then epilogue
#pragma unroll
    for (int j = 0; j < 4; ++j) {
        float lt = li[j];
        lt += __shfl_xor(lt, 1, 64);
        lt += __shfl_xor(lt, 2, 64);
        lt += __shfl_xor(lt, 4, 64);
        lt += __shfl_xor(lt, 8, 64);
        const float inv = 1.f / lt;
        const int t = q0 + w * 16 + 4 * g + j;
        float* op = out + (((size_t)b * NT + t) * NHEADS + h) * HDIM;
#pragma unroll
        for (int dt = 0; dt < 4; ++dt) op[dt * 16 + fr] = acc[dt][j] * inv;
    }
}

extern "C" void kernel_launch(void* const* d_in, const int* in_sizes, int n_in,
                              void* d_out, int out_size, void* d_ws, size_t ws_size,
                              hipStream_t stream) {
    const float* x        = (const float*)d_in[0];
    const float* pe_cos   = (const float*)d_in[1];
    const float* pe_sin   = (const float*)d_in[2];
    const float* pe_scale = (const float*)d_in[3];
    const float* mask     = (const float*)d_in[4];
    const float* w_qkv    = (const float*)d_in[5];
    const float* b_qkv    = (const float*)d_in[6];
    float* out = (float*)d_out;

    unsigned short* ws = (unsigned short*)d_ws;
    const size_t PER = (size_t)NB * NHEADS * NT * HDIM;   // 8388608
    unsigned short* qbuf = ws;
    unsigned short* kbuf = ws + PER;
    unsigned short* vtbuf = ws + 2 * PER;
    unsigned short* xbuf = ws + 3 * PER;                  // 8192*1024 fp16
    unsigned short* wbuf = ws + 4 * PER;                  // 3072*1024 fp16

    conv_f16_kernel<<<8192, 256, 0, stream>>>(x, xbuf, (NB * NT * NC) / 4);
    conv_f16_kernel<<<3072, 256, 0, stream>>>(w_qkv, wbuf, (3 * NC * NC) / 4);
    qkv_gemm_kernel<<<1536, 256, 0, stream>>>(xbuf, wbuf, b_qkv,
                                              pe_cos, pe_sin, pe_scale,
                                              qbuf, kbuf, vtbuf);
    attn_mfma_kernel<<<2048, 256, 0, stream>>>(qbuf, kbuf, vtbuf, mask, out);
}